// Round 16
// baseline (244.047 us; speedup 1.0000x reference)
//
#include <hip/hip_runtime.h>
#include <stdint.h>
#include <stddef.h>

#define HW   16384
#define W_   256
#define H_   64
#define C_   128
#define B_   2
#define WP   258
#define MAXI 17027.0f

// ---------- order-preserving float<->uint map (for atomic min/max) ----------
__device__ __forceinline__ uint32_t fkey(float f) {
    uint32_t u = __float_as_uint(f);
    return (u & 0x80000000u) ? ~u : (u | 0x80000000u);
}
__device__ __forceinline__ float funkey(uint32_t k) {
    uint32_t u = (k & 0x80000000u) ? (k ^ 0x80000000u) : ~k;
    return __uint_as_float(u);
}

// ---------- global min/max of x_range channels 0 (rx) and 1 (ry) ----------
// mm layout: [0]=rx_min_key [1]=ry_min_key [2]=rx_max_key [3]=ry_max_key
__global__ void __launch_bounds__(256) minmax_kernel(const float* __restrict__ xr,
                                                     uint32_t* __restrict__ mm) {
    float rxmin = 1e30f, rxmax = -1e30f, rymin = 1e30f, rymax = -1e30f;
    const int stride = gridDim.x * blockDim.x;
    for (int t = blockIdx.x * blockDim.x + threadIdx.x; t < B_ * HW; t += stride) {
        const int b = t >> 14, p = t & (HW - 1);
        const float rx = xr[b * 2 * HW + p];
        const float ry = xr[b * 2 * HW + HW + p];
        rxmin = fminf(rxmin, rx); rxmax = fmaxf(rxmax, rx);
        rymin = fminf(rymin, ry); rymax = fmaxf(rymax, ry);
    }
    #pragma unroll
    for (int off = 32; off; off >>= 1) {
        rxmin = fminf(rxmin, __shfl_xor(rxmin, off));
        rxmax = fmaxf(rxmax, __shfl_xor(rxmax, off));
        rymin = fminf(rymin, __shfl_xor(rymin, off));
        rymax = fmaxf(rymax, __shfl_xor(rymax, off));
    }
    if ((threadIdx.x & 63) == 0) {
        atomicMin(&mm[0], fkey(rxmin));
        atomicMin(&mm[1], fkey(rymin));
        atomicMax(&mm[2], fkey(rxmax));
        atomicMax(&mm[3], fkey(rymax));
    }
}

// ---------- shift_x: per-pixel 9-tap x 4-gather, channel-independent table ----------
// Recipe "F" (R8-R15 elimination: ref has f32-rounded off_v/floors; offsets
// not A/B/D/f64): RECIPROCAL-MULTIPLY offsets -- q = RN32(3/d),
// off = RN32(Delta*q). This is XLA's algebraic-simplifier form of
// (D_MAX*(rx-min))/(max-min) (divide-by-runtime-scalar -> mul-by-reciprocal).
// Composition/after/weights: all f32, numpy broadcast order (t2 pre-rounded).
__global__ void __launch_bounds__(256) shift_kernel(
    const float* __restrict__ x, const float* __restrict__ xr,
    const float* __restrict__ ro, const uint32_t* __restrict__ mm,
    float* __restrict__ out)
{
#pragma clang fp contract(off)
    const int cs   = blockIdx.x & 7;        // channel split 0..7 (16 ch each)
    const int pblk = blockIdx.x >> 3;       // pixel block 0..127
    const int pix  = pblk * 256 + (int)threadIdx.x;
    const int b = pix >> 14;
    const int p = pix & (HW - 1);
    const int i = p >> 8;
    const int j = p & 255;

    int   offs[9][4];
    float coef[9][4];
    {
        const float rxmin = funkey(mm[0]);
        const float rymin = funkey(mm[1]);
        const float rxmax = funkey(mm[2]);
        const float rymax = funkey(mm[3]);
        const float rx = xr[b * 2 * HW + p];
        const float ry = xr[b * 2 * HW + HW + p];
        // F-offsets: reciprocal-multiply, all IEEE f32 RN.
        const float dx = __fsub_rn(rxmax, rxmin);
        const float dy = __fsub_rn(rymax, rymin);
        const float qx = __fdiv_rn(3.0f, dx);
        const float qy = __fdiv_rn(3.0f, dy);
        const float offx = __fmul_rn(__fsub_rn(rx, rxmin), qx);
        const float offy = __fmul_rn(__fsub_rn(ry, rymin), qy);

        const int ixo[9] = {-1, 0, 1, -1, 0, 1, -1, 0, 1};
        const int iyo[9] = {-1, -1, -1, 0, 0, 0, 1, 1, 1};
#pragma unroll
        for (int k = 0; k < 9; ++k) {
            const float xo = (float)ixo[k];
            // pre = v + x_off + y_off*w + 2, v = (i+1)*wp + (j+1)   [w=256, wp=258]
            const int pre_i = (i + 1) * WP + (j + 1) + ixo[k] + iyo[k] * W_ + 2;
            const float pre = (float)pre_i;                       // exact
            const float t1   = __fmul_rn(offx, xo);               // exact (xo in {-1,0,1})
            const float t2   = __fmul_rn(offy, (float)(iyo[k] * WP)); // yo*258 exact
            const float offv = __fadd_rn(t1, t2);
            const float after = __fadd_rn(pre, offv);
            const float fl = floorf(offv), ce = ceilf(offv);
            const float a_f  = fminf(fmaxf(__fadd_rn(pre, fl), 0.0f), MAXI);
            const float a_f1 = fminf(fmaxf(__fadd_rn(a_f, xo), 0.0f), MAXI);  // ints: exact
            const float a_c  = fminf(fmaxf(__fadd_rn(pre, ce), 0.0f), MAXI);
            const float a_c1 = fminf(fmaxf(__fadd_rn(a_c, xo), 0.0f), MAXI);
            const float wf  = fabsf(__fsub_rn(after, a_f));
            const float wf1 = fabsf(__fsub_rn(a_f1, after));
            const float wc1 = fabsf(__fsub_rn(after, a_c1));
            const float wc  = fabsf(__fsub_rn(a_c, after));
            const float s1  = __fdiv_rn(wf,  258.0f);   // |RN(d)/258|, sign-symmetric
            const float s2  = __fdiv_rn(wc1, 258.0f);
            coef[k][0] = __fmul_rn(s1, wf);    // * v(a_f)
            coef[k][1] = __fmul_rn(s1, wf1);   // * v(a_f1)
            coef[k][2] = __fmul_rn(s2, wc1);   // * v(a_c1)
            coef[k][3] = __fmul_rn(s2, wc);    // * v(a_c)
            const float av[4] = {a_f, a_f1, a_c1, a_c};
#pragma unroll
            for (int q = 0; q < 4; ++q) {
                const int ii = (int)av[q];               // exact ints in [0,17027]
                const int ip = ii / WP;
                const int jp = ii - ip * WP;
                offs[k][q] = (ip >= 1 && ip <= H_ && jp >= 1 && jp <= W_)
                           ? ((ip - 1) << 8) + (jp - 1) : -1;   // -1 => pad zero
            }
        }
    }

    const int c0 = cs * 16;
    for (int c = c0; c < c0 + 16; ++c) {
        const float* xc = x + (((size_t)(b * C_ + c)) << 14);
        float acc = 0.0f;
#pragma unroll
        for (int k = 0; k < 9; ++k) {
            const float v0 = offs[k][0] >= 0 ? xc[offs[k][0]] : 0.0f;
            const float v1 = offs[k][1] >= 0 ? xc[offs[k][1]] : 0.0f;
            const float v2 = offs[k][2] >= 0 ? xc[offs[k][2]] : 0.0f;
            const float v3 = offs[k][3] >= 0 ? xc[offs[k][3]] : 0.0f;
            const float g = coef[k][0] * v0 + coef[k][1] * v1
                          + coef[k][2] * v2 + coef[k][3] * v3;
            acc = acc + g * ro[c * 9 + k];
        }
        out[(((size_t)(b * C_ + c)) << 14) + p] = acc;
    }
}

// ---------- pointwise 1x1 conv (in-place safe): block stages its full tile ----------
__global__ void __launch_bounds__(256) pw_kernel(
    const float* __restrict__ in, const float* __restrict__ w,
    const float* __restrict__ bias, float* __restrict__ out)
{
    __shared__ float lds[C_ * 64];
    const int b  = blockIdx.x >> 8;
    const int p0 = (blockIdx.x & 255) * 64;
    const int tid = threadIdx.x;

    for (int idx = tid; idx < C_ * 64; idx += 256) {
        const int ci = idx >> 6, px = idx & 63;
        lds[idx] = in[(((size_t)(b * C_ + ci)) << 14) + p0 + px];
    }
    __syncthreads();

    const int px4 = (tid & 15) * 4;       // 4 consecutive pixels
    const int co0 = (tid >> 4) * 8;       // 8 consecutive out-channels

    float acc[8][4];
#pragma unroll
    for (int q = 0; q < 8; ++q) {
        const float bv = bias[co0 + q];
        acc[q][0] = bv; acc[q][1] = bv; acc[q][2] = bv; acc[q][3] = bv;
    }

    for (int ci = 0; ci < C_; ci += 4) {
        float xvv[4][4];
#pragma unroll
        for (int jc = 0; jc < 4; ++jc) {
            const float4 t = *(const float4*)&lds[(ci + jc) * 64 + px4];
            xvv[jc][0] = t.x; xvv[jc][1] = t.y; xvv[jc][2] = t.z; xvv[jc][3] = t.w;
        }
#pragma unroll
        for (int q = 0; q < 8; ++q) {
            const float4 wv = *(const float4*)&w[(co0 + q) * C_ + ci];
#pragma unroll
            for (int jp = 0; jp < 4; ++jp) {
                acc[q][jp] += wv.x * xvv[0][jp] + wv.y * xvv[1][jp]
                            + wv.z * xvv[2][jp] + wv.w * xvv[3][jp];
            }
        }
    }

#pragma unroll
    for (int q = 0; q < 8; ++q) {
        float4 o; o.x = acc[q][0]; o.y = acc[q][1]; o.z = acc[q][2]; o.w = acc[q][3];
        *(float4*)&out[(((size_t)(b * C_ + co0 + q)) << 14) + p0 + px4] = o;
    }
}

// ---------- depthwise 3x3, pad=1 ----------
__global__ void __launch_bounds__(256) dw_kernel(
    const float* __restrict__ in, const float* __restrict__ w,
    const float* __restrict__ bias, float* __restrict__ out)
{
    const int idx = blockIdx.x * 256 + (int)threadIdx.x;
    const int xx = idx & 255;
    const int y  = (idx >> 8) & 63;
    const int bc = idx >> 14;            // 0..255 (b*128+c)
    const int c  = bc & (C_ - 1);
    const size_t base = ((size_t)bc) << 14;

    float acc = bias[c];
#pragma unroll
    for (int ky = 0; ky < 3; ++ky) {
        const int yy = y + ky - 1;
        if (yy < 0 || yy >= H_) continue;
#pragma unroll
        for (int kx = 0; kx < 3; ++kx) {
            const int x2 = xx + kx - 1;
            if (x2 < 0 || x2 >= W_) continue;
            acc += w[c * 9 + ky * 3 + kx] * in[base + yy * 256 + x2];
        }
    }
    out[base + (y << 8) + xx] = acc;
}

extern "C" void kernel_launch(void* const* d_in, const int* in_sizes, int n_in,
                              void* d_out, int out_size, void* d_ws, size_t ws_size,
                              hipStream_t stream) {
    (void)in_sizes; (void)n_in; (void)out_size; (void)ws_size;
    const float* x     = (const float*)d_in[0];
    const float* xr    = (const float*)d_in[1];
    const float* ro    = (const float*)d_in[2];
    const float* w_rc  = (const float*)d_in[3];
    const float* b_rc  = (const float*)d_in[4];
    const float* w_dw1 = (const float*)d_in[5];
    const float* b_dw1 = (const float*)d_in[6];
    const float* w_pw1 = (const float*)d_in[7];
    const float* b_pw1 = (const float*)d_in[8];
    const float* w_dw2 = (const float*)d_in[9];
    const float* b_dw2 = (const float*)d_in[10];
    const float* w_pw2 = (const float*)d_in[11];
    const float* b_pw2 = (const float*)d_in[12];
    float* outp = (float*)d_out;

    // mm lives in the HEAD OF D_OUT (16 bytes) — consumed by shift_kernel and
    // dead before dw1 overwrites d_out. Workspace holds exactly ONE tensor.
    uint32_t* mm = (uint32_t*)d_out;
    float* bufA  = (float*)d_ws;

    // re-init min/max slots every call (nothing is re-poisoned between replays)
    hipMemsetAsync(mm, 0xFF, 8, stream);       // min slots -> max key
    hipMemsetAsync(mm + 2, 0x00, 8, stream);   // max slots -> min key

    minmax_kernel<<<64, 256, 0, stream>>>(xr, mm);
    shift_kernel<<<128 * 8, 256, 0, stream>>>(x, xr, ro, mm, bufA); // x -> ws
    pw_kernel<<<512, 256, 0, stream>>>(bufA, w_rc, b_rc, bufA);     // in-place (ws)
    dw_kernel<<<16384, 256, 0, stream>>>(bufA, w_dw1, b_dw1, outp); // ws -> out (kills mm)
    pw_kernel<<<512, 256, 0, stream>>>(outp, w_pw1, b_pw1, outp);   // in-place (out)
    dw_kernel<<<16384, 256, 0, stream>>>(outp, w_dw2, b_dw2, bufA); // out -> ws
    pw_kernel<<<512, 256, 0, stream>>>(bufA, w_pw2, b_pw2, outp);   // ws -> out (final)
}

// Round 17
// 242.006 us; speedup vs baseline: 1.0084x; 1.0084x over previous
//
#include <hip/hip_runtime.h>
#include <stdint.h>
#include <stddef.h>

#define HW   16384
#define W_   256
#define H_   64
#define C_   128
#define B_   2
#define WP   258
#define MAXI 17027.0f

// ---------- order-preserving float<->uint map (for atomic min/max) ----------
__device__ __forceinline__ uint32_t fkey(float f) {
    uint32_t u = __float_as_uint(f);
    return (u & 0x80000000u) ? ~u : (u | 0x80000000u);
}
__device__ __forceinline__ float funkey(uint32_t k) {
    uint32_t u = (k & 0x80000000u) ? (k ^ 0x80000000u) : ~k;
    return __uint_as_float(u);
}

// ---------- global min/max of x_range channels 0 (rx) and 1 (ry) ----------
// mm layout: [0]=rx_min_key [1]=ry_min_key [2]=rx_max_key [3]=ry_max_key
__global__ void __launch_bounds__(256) minmax_kernel(const float* __restrict__ xr,
                                                     uint32_t* __restrict__ mm) {
    float rxmin = 1e30f, rxmax = -1e30f, rymin = 1e30f, rymax = -1e30f;
    const int stride = gridDim.x * blockDim.x;
    for (int t = blockIdx.x * blockDim.x + threadIdx.x; t < B_ * HW; t += stride) {
        const int b = t >> 14, p = t & (HW - 1);
        const float rx = xr[b * 2 * HW + p];
        const float ry = xr[b * 2 * HW + HW + p];
        rxmin = fminf(rxmin, rx); rxmax = fmaxf(rxmax, rx);
        rymin = fminf(rymin, ry); rymax = fmaxf(rymax, ry);
    }
    #pragma unroll
    for (int off = 32; off; off >>= 1) {
        rxmin = fminf(rxmin, __shfl_xor(rxmin, off));
        rxmax = fmaxf(rxmax, __shfl_xor(rxmax, off));
        rymin = fminf(rymin, __shfl_xor(rymin, off));
        rymax = fmaxf(rymax, __shfl_xor(rymax, off));
    }
    if ((threadIdx.x & 63) == 0) {
        atomicMin(&mm[0], fkey(rxmin));
        atomicMin(&mm[1], fkey(rymin));
        atomicMax(&mm[2], fkey(rxmax));
        atomicMax(&mm[3], fkey(rymax));
    }
}

// ---------- shift_x: per-pixel 9-tap x 4-gather, channel-independent table ----------
// NUMERICS LOCKED (R16 pass): recipe "F" -- reciprocal-multiply offsets
// q = RN32(3/d), off = RN32(Delta*q); f32 composition with t2 pre-rounded;
// f32 after/weights. Do NOT alter any table op or its order.
// R17: cs split 8 -> 16 (grid 2048 = 8 blocks/CU) for latency hiding; the
// gather phase is latency-bound (Occ 25%, VALU 21%, HBM 3% at R16).
__global__ void __launch_bounds__(256) shift_kernel(
    const float* __restrict__ x, const float* __restrict__ xr,
    const float* __restrict__ ro, const uint32_t* __restrict__ mm,
    float* __restrict__ out)
{
#pragma clang fp contract(off)
    const int cs   = blockIdx.x & 15;       // channel split 0..15 (8 ch each)
    const int pblk = blockIdx.x >> 4;       // pixel block 0..127
    const int pix  = pblk * 256 + (int)threadIdx.x;
    const int b = pix >> 14;
    const int p = pix & (HW - 1);
    const int i = p >> 8;
    const int j = p & 255;

    int   offs[9][4];
    float coef[9][4];
    {
        const float rxmin = funkey(mm[0]);
        const float rymin = funkey(mm[1]);
        const float rxmax = funkey(mm[2]);
        const float rymax = funkey(mm[3]);
        const float rx = xr[b * 2 * HW + p];
        const float ry = xr[b * 2 * HW + HW + p];
        // F-offsets: reciprocal-multiply, all IEEE f32 RN.
        const float dx = __fsub_rn(rxmax, rxmin);
        const float dy = __fsub_rn(rymax, rymin);
        const float qx = __fdiv_rn(3.0f, dx);
        const float qy = __fdiv_rn(3.0f, dy);
        const float offx = __fmul_rn(__fsub_rn(rx, rxmin), qx);
        const float offy = __fmul_rn(__fsub_rn(ry, rymin), qy);

        const int ixo[9] = {-1, 0, 1, -1, 0, 1, -1, 0, 1};
        const int iyo[9] = {-1, -1, -1, 0, 0, 0, 1, 1, 1};
#pragma unroll
        for (int k = 0; k < 9; ++k) {
            const float xo = (float)ixo[k];
            // pre = v + x_off + y_off*w + 2, v = (i+1)*wp + (j+1)   [w=256, wp=258]
            const int pre_i = (i + 1) * WP + (j + 1) + ixo[k] + iyo[k] * W_ + 2;
            const float pre = (float)pre_i;                       // exact
            const float t1   = __fmul_rn(offx, xo);               // exact (xo in {-1,0,1})
            const float t2   = __fmul_rn(offy, (float)(iyo[k] * WP)); // yo*258 exact
            const float offv = __fadd_rn(t1, t2);
            const float after = __fadd_rn(pre, offv);
            const float fl = floorf(offv), ce = ceilf(offv);
            const float a_f  = fminf(fmaxf(__fadd_rn(pre, fl), 0.0f), MAXI);
            const float a_f1 = fminf(fmaxf(__fadd_rn(a_f, xo), 0.0f), MAXI);  // ints: exact
            const float a_c  = fminf(fmaxf(__fadd_rn(pre, ce), 0.0f), MAXI);
            const float a_c1 = fminf(fmaxf(__fadd_rn(a_c, xo), 0.0f), MAXI);
            const float wf  = fabsf(__fsub_rn(after, a_f));
            const float wf1 = fabsf(__fsub_rn(a_f1, after));
            const float wc1 = fabsf(__fsub_rn(after, a_c1));
            const float wc  = fabsf(__fsub_rn(a_c, after));
            const float s1  = __fdiv_rn(wf,  258.0f);   // |RN(d)/258|, sign-symmetric
            const float s2  = __fdiv_rn(wc1, 258.0f);
            coef[k][0] = __fmul_rn(s1, wf);    // * v(a_f)
            coef[k][1] = __fmul_rn(s1, wf1);   // * v(a_f1)
            coef[k][2] = __fmul_rn(s2, wc1);   // * v(a_c1)
            coef[k][3] = __fmul_rn(s2, wc);    // * v(a_c)
            const float av[4] = {a_f, a_f1, a_c1, a_c};
#pragma unroll
            for (int q = 0; q < 4; ++q) {
                const int ii = (int)av[q];               // exact ints in [0,17027]
                const int ip = ii / WP;
                const int jp = ii - ip * WP;
                offs[k][q] = (ip >= 1 && ip <= H_ && jp >= 1 && jp <= W_)
                           ? ((ip - 1) << 8) + (jp - 1) : -1;   // -1 => pad zero
            }
        }
    }

    const int c0 = cs * 8;
    for (int c = c0; c < c0 + 8; ++c) {
        const float* xc = x + (((size_t)(b * C_ + c)) << 14);
        float acc = 0.0f;
#pragma unroll
        for (int k = 0; k < 9; ++k) {
            const float v0 = offs[k][0] >= 0 ? xc[offs[k][0]] : 0.0f;
            const float v1 = offs[k][1] >= 0 ? xc[offs[k][1]] : 0.0f;
            const float v2 = offs[k][2] >= 0 ? xc[offs[k][2]] : 0.0f;
            const float v3 = offs[k][3] >= 0 ? xc[offs[k][3]] : 0.0f;
            const float g = coef[k][0] * v0 + coef[k][1] * v1
                          + coef[k][2] * v2 + coef[k][3] * v3;
            acc = acc + g * ro[c * 9 + k];
        }
        out[(((size_t)(b * C_ + c)) << 14) + p] = acc;
    }
}

// ---------- pointwise 1x1 conv (in-place safe): block stages its full tile ----------
__global__ void __launch_bounds__(256) pw_kernel(
    const float* __restrict__ in, const float* __restrict__ w,
    const float* __restrict__ bias, float* __restrict__ out)
{
    __shared__ float lds[C_ * 64];
    const int b  = blockIdx.x >> 8;
    const int p0 = (blockIdx.x & 255) * 64;
    const int tid = threadIdx.x;

    for (int idx = tid; idx < C_ * 64; idx += 256) {
        const int ci = idx >> 6, px = idx & 63;
        lds[idx] = in[(((size_t)(b * C_ + ci)) << 14) + p0 + px];
    }
    __syncthreads();

    const int px4 = (tid & 15) * 4;       // 4 consecutive pixels
    const int co0 = (tid >> 4) * 8;       // 8 consecutive out-channels

    float acc[8][4];
#pragma unroll
    for (int q = 0; q < 8; ++q) {
        const float bv = bias[co0 + q];
        acc[q][0] = bv; acc[q][1] = bv; acc[q][2] = bv; acc[q][3] = bv;
    }

    for (int ci = 0; ci < C_; ci += 4) {
        float xvv[4][4];
#pragma unroll
        for (int jc = 0; jc < 4; ++jc) {
            const float4 t = *(const float4*)&lds[(ci + jc) * 64 + px4];
            xvv[jc][0] = t.x; xvv[jc][1] = t.y; xvv[jc][2] = t.z; xvv[jc][3] = t.w;
        }
#pragma unroll
        for (int q = 0; q < 8; ++q) {
            const float4 wv = *(const float4*)&w[(co0 + q) * C_ + ci];
#pragma unroll
            for (int jp = 0; jp < 4; ++jp) {
                acc[q][jp] += wv.x * xvv[0][jp] + wv.y * xvv[1][jp]
                            + wv.z * xvv[2][jp] + wv.w * xvv[3][jp];
            }
        }
    }

#pragma unroll
    for (int q = 0; q < 8; ++q) {
        float4 o; o.x = acc[q][0]; o.y = acc[q][1]; o.z = acc[q][2]; o.w = acc[q][3];
        *(float4*)&out[(((size_t)(b * C_ + co0 + q)) << 14) + p0 + px4] = o;
    }
}

// ---------- depthwise 3x3, pad=1 ----------
__global__ void __launch_bounds__(256) dw_kernel(
    const float* __restrict__ in, const float* __restrict__ w,
    const float* __restrict__ bias, float* __restrict__ out)
{
    const int idx = blockIdx.x * 256 + (int)threadIdx.x;
    const int xx = idx & 255;
    const int y  = (idx >> 8) & 63;
    const int bc = idx >> 14;            // 0..255 (b*128+c)
    const int c  = bc & (C_ - 1);
    const size_t base = ((size_t)bc) << 14;

    float acc = bias[c];
#pragma unroll
    for (int ky = 0; ky < 3; ++ky) {
        const int yy = y + ky - 1;
        if (yy < 0 || yy >= H_) continue;
#pragma unroll
        for (int kx = 0; kx < 3; ++kx) {
            const int x2 = xx + kx - 1;
            if (x2 < 0 || x2 >= W_) continue;
            acc += w[c * 9 + ky * 3 + kx] * in[base + yy * 256 + x2];
        }
    }
    out[base + (y << 8) + xx] = acc;
}

extern "C" void kernel_launch(void* const* d_in, const int* in_sizes, int n_in,
                              void* d_out, int out_size, void* d_ws, size_t ws_size,
                              hipStream_t stream) {
    (void)in_sizes; (void)n_in; (void)out_size; (void)ws_size;
    const float* x     = (const float*)d_in[0];
    const float* xr    = (const float*)d_in[1];
    const float* ro    = (const float*)d_in[2];
    const float* w_rc  = (const float*)d_in[3];
    const float* b_rc  = (const float*)d_in[4];
    const float* w_dw1 = (const float*)d_in[5];
    const float* b_dw1 = (const float*)d_in[6];
    const float* w_pw1 = (const float*)d_in[7];
    const float* b_pw1 = (const float*)d_in[8];
    const float* w_dw2 = (const float*)d_in[9];
    const float* b_dw2 = (const float*)d_in[10];
    const float* w_pw2 = (const float*)d_in[11];
    const float* b_pw2 = (const float*)d_in[12];
    float* outp = (float*)d_out;

    // mm lives in the HEAD OF D_OUT (16 bytes) — consumed by shift_kernel and
    // dead before dw1 overwrites d_out. Workspace holds exactly ONE tensor.
    uint32_t* mm = (uint32_t*)d_out;
    float* bufA  = (float*)d_ws;

    // re-init min/max slots every call (nothing is re-poisoned between replays)
    hipMemsetAsync(mm, 0xFF, 8, stream);       // min slots -> max key
    hipMemsetAsync(mm + 2, 0x00, 8, stream);   // max slots -> min key

    minmax_kernel<<<64, 256, 0, stream>>>(xr, mm);
    shift_kernel<<<128 * 16, 256, 0, stream>>>(x, xr, ro, mm, bufA); // x -> ws
    pw_kernel<<<512, 256, 0, stream>>>(bufA, w_rc, b_rc, bufA);     // in-place (ws)
    dw_kernel<<<16384, 256, 0, stream>>>(bufA, w_dw1, b_dw1, outp); // ws -> out (kills mm)
    pw_kernel<<<512, 256, 0, stream>>>(outp, w_pw1, b_pw1, outp);   // in-place (out)
    dw_kernel<<<16384, 256, 0, stream>>>(outp, w_dw2, b_dw2, bufA); // out -> ws
    pw_kernel<<<512, 256, 0, stream>>>(bufA, w_pw2, b_pw2, outp);   // ws -> out (final)
}

// Round 19
// 177.005 us; speedup vs baseline: 1.3788x; 1.3672x over previous
//
#include <hip/hip_runtime.h>
#include <stdint.h>
#include <stddef.h>

#define HW   16384
#define W_   256
#define H_   64
#define C_   128
#define B_   2
#define WP   258
#define MAXI 17027.0f

typedef float f4v __attribute__((ext_vector_type(4), aligned(4)));

// ---------- order-preserving float<->uint map (for atomic min/max) ----------
__device__ __forceinline__ uint32_t fkey(float f) {
    uint32_t u = __float_as_uint(f);
    return (u & 0x80000000u) ? ~u : (u | 0x80000000u);
}
__device__ __forceinline__ float funkey(uint32_t k) {
    uint32_t u = (k & 0x80000000u) ? (k ^ 0x80000000u) : ~k;
    return __uint_as_float(u);
}

// ---------- global min/max of x_range channels 0 (rx) and 1 (ry) ----------
__global__ void __launch_bounds__(256) minmax_kernel(const float* __restrict__ xr,
                                                     uint32_t* __restrict__ mm) {
    float rxmin = 1e30f, rxmax = -1e30f, rymin = 1e30f, rymax = -1e30f;
    const int stride = gridDim.x * blockDim.x;
    for (int t = blockIdx.x * blockDim.x + threadIdx.x; t < B_ * HW; t += stride) {
        const int b = t >> 14, p = t & (HW - 1);
        const float rx = xr[b * 2 * HW + p];
        const float ry = xr[b * 2 * HW + HW + p];
        rxmin = fminf(rxmin, rx); rxmax = fmaxf(rxmax, rx);
        rymin = fminf(rymin, ry); rymax = fmaxf(rymax, ry);
    }
    #pragma unroll
    for (int off = 32; off; off >>= 1) {
        rxmin = fminf(rxmin, __shfl_xor(rxmin, off));
        rxmax = fmaxf(rxmax, __shfl_xor(rxmax, off));
        rymin = fminf(rymin, __shfl_xor(rymin, off));
        rymax = fmaxf(rymax, __shfl_xor(rymax, off));
    }
    if ((threadIdx.x & 63) == 0) {
        atomicMin(&mm[0], fkey(rxmin));
        atomicMin(&mm[1], fkey(rymin));
        atomicMax(&mm[2], fkey(rxmax));
        atomicMax(&mm[3], fkey(rymax));
    }
}

// ---------- shift_x ----------
// NUMERICS LOCKED (R16 pass): recipe "F" table ops/order untouched.
// R19: per-tap WEIGHT REGROUPING replaces R18's selector machinery:
//   bs = min(min_valid_offs, HW-4);  w_i = sum_q (offs_q - bs == i ? coef_q : 0)
// Invalid taps (offs=-1) give d<0 -> excluded exactly (== v=0 semantics), so
// the channel loop is BRANCHLESS: one dwordx4 + 4-term dot per tap-channel.
// VMEM insts 36 -> 9 per channel-pixel (TA throughput was the bottleneck:
// 28cyc/inst, HBM 3%, VALU 27%, occupancy-insensitive per R17).
// Reassociation delta ~1ulp/tap -> ~1e-10 at output (threshold margin 4e-7).
__global__ void __launch_bounds__(256) shift_kernel(
    const float* __restrict__ x, const float* __restrict__ xr,
    const float* __restrict__ ro, const uint32_t* __restrict__ mm,
    float* __restrict__ out)
{
#pragma clang fp contract(off)
    const int cs   = blockIdx.x & 15;       // channel split 0..15 (8 ch each)
    const int pblk = blockIdx.x >> 4;       // pixel block 0..127
    const int pix  = pblk * 256 + (int)threadIdx.x;
    const int b = pix >> 14;
    const int p = pix & (HW - 1);
    const int i = p >> 8;
    const int j = p & 255;

    int   bs9[9];
    float w9[9][4];
    {
        const float rxmin = funkey(mm[0]);
        const float rymin = funkey(mm[1]);
        const float rxmax = funkey(mm[2]);
        const float rymax = funkey(mm[3]);
        const float rx = xr[b * 2 * HW + p];
        const float ry = xr[b * 2 * HW + HW + p];
        // F-offsets: reciprocal-multiply, all IEEE f32 RN.  (LOCKED)
        const float dx = __fsub_rn(rxmax, rxmin);
        const float dy = __fsub_rn(rymax, rymin);
        const float qx = __fdiv_rn(3.0f, dx);
        const float qy = __fdiv_rn(3.0f, dy);
        const float offx = __fmul_rn(__fsub_rn(rx, rxmin), qx);
        const float offy = __fmul_rn(__fsub_rn(ry, rymin), qy);

        const int ixo[9] = {-1, 0, 1, -1, 0, 1, -1, 0, 1};
        const int iyo[9] = {-1, -1, -1, 0, 0, 0, 1, 1, 1};
#pragma unroll
        for (int k = 0; k < 9; ++k) {
            const float xo = (float)ixo[k];
            const int pre_i = (i + 1) * WP + (j + 1) + ixo[k] + iyo[k] * W_ + 2;
            const float pre = (float)pre_i;                       // exact
            const float t1   = __fmul_rn(offx, xo);               // exact
            const float t2   = __fmul_rn(offy, (float)(iyo[k] * WP)); // exact
            const float offv = __fadd_rn(t1, t2);
            const float after = __fadd_rn(pre, offv);
            const float fl = floorf(offv), ce = ceilf(offv);
            const float a_f  = fminf(fmaxf(__fadd_rn(pre, fl), 0.0f), MAXI);
            const float a_f1 = fminf(fmaxf(__fadd_rn(a_f, xo), 0.0f), MAXI);
            const float a_c  = fminf(fmaxf(__fadd_rn(pre, ce), 0.0f), MAXI);
            const float a_c1 = fminf(fmaxf(__fadd_rn(a_c, xo), 0.0f), MAXI);
            const float wf  = fabsf(__fsub_rn(after, a_f));
            const float wf1 = fabsf(__fsub_rn(a_f1, after));
            const float wc1 = fabsf(__fsub_rn(after, a_c1));
            const float wc  = fabsf(__fsub_rn(a_c, after));
            const float s1  = __fdiv_rn(wf,  258.0f);
            const float s2  = __fdiv_rn(wc1, 258.0f);
            const float cf0 = __fmul_rn(s1, wf);    // * v(a_f)
            const float cf1 = __fmul_rn(s1, wf1);   // * v(a_f1)
            const float cf2 = __fmul_rn(s2, wc1);   // * v(a_c1)
            const float cf3 = __fmul_rn(s2, wc);    // * v(a_c)
            const float av[4] = {a_f, a_f1, a_c1, a_c};
            int off4[4];
#pragma unroll
            for (int q = 0; q < 4; ++q) {
                const int ii = (int)av[q];               // exact ints in [0,17027]
                const int ip = ii / WP;
                const int jp = ii - ip * WP;
                off4[q] = (ip >= 1 && ip <= H_ && jp >= 1 && jp <= W_)
                        ? ((ip - 1) << 8) + (jp - 1) : -1;   // -1 => pad zero
            }
            // regroup: base = min valid offset (clamped for safe x4 window)
            const int mq0 = off4[0] < 0 ? 0x7FFFFFFF : off4[0];
            const int mq1 = off4[1] < 0 ? 0x7FFFFFFF : off4[1];
            const int mq2 = off4[2] < 0 ? 0x7FFFFFFF : off4[2];
            const int mq3 = off4[3] < 0 ? 0x7FFFFFFF : off4[3];
            const int mv = min(min(mq0, mq1), min(mq2, mq3));
            const int bs = min(mv, HW - 4);          // all-invalid -> HW-4, w=0
            const int d0 = off4[0] - bs;             // invalid -> negative
            const int d1 = off4[1] - bs;
            const int d2 = off4[2] - bs;
            const int d3 = off4[3] - bs;
            w9[k][0] = (d0 == 0 ? cf0 : 0.0f) + (d1 == 0 ? cf1 : 0.0f)
                     + (d2 == 0 ? cf2 : 0.0f) + (d3 == 0 ? cf3 : 0.0f);
            w9[k][1] = (d0 == 1 ? cf0 : 0.0f) + (d1 == 1 ? cf1 : 0.0f)
                     + (d2 == 1 ? cf2 : 0.0f) + (d3 == 1 ? cf3 : 0.0f);
            w9[k][2] = (d0 == 2 ? cf0 : 0.0f) + (d1 == 2 ? cf1 : 0.0f)
                     + (d2 == 2 ? cf2 : 0.0f) + (d3 == 2 ? cf3 : 0.0f);
            w9[k][3] = (d0 == 3 ? cf0 : 0.0f) + (d1 == 3 ? cf1 : 0.0f)
                     + (d2 == 3 ? cf2 : 0.0f) + (d3 == 3 ? cf3 : 0.0f);
            bs9[k] = bs;
        }
    }

    const int c0 = cs * 8;
    const float* xb = x + (((size_t)(b * C_ + c0)) << 14);

    float acc[8];
#pragma unroll
    for (int c8 = 0; c8 < 8; ++c8) acc[c8] = 0.0f;

    {
#pragma clang fp contract(fast)
#pragma unroll
        for (int k = 0; k < 9; ++k) {
            const int bk = bs9[k];
#pragma unroll
            for (int c8 = 0; c8 < 8; ++c8) {
                const f4v t = *(const f4v*)(xb + (((size_t)c8) << 14) + bk);
                const float g = w9[k][0] * t.x + w9[k][1] * t.y
                              + w9[k][2] * t.z + w9[k][3] * t.w;
                acc[c8] += g * ro[(c0 + c8) * 9 + k];
            }
        }
    }

#pragma unroll
    for (int c8 = 0; c8 < 8; ++c8)
        out[(((size_t)(b * C_ + c0 + c8)) << 14) + p] = acc[c8];
}

// ---------- pointwise 1x1 conv (in-place safe): block stages its full tile ----------
__global__ void __launch_bounds__(256) pw_kernel(
    const float* __restrict__ in, const float* __restrict__ w,
    const float* __restrict__ bias, float* __restrict__ out)
{
    __shared__ float lds[C_ * 64];
    const int b  = blockIdx.x >> 8;
    const int p0 = (blockIdx.x & 255) * 64;
    const int tid = threadIdx.x;

    for (int idx = tid; idx < C_ * 64; idx += 256) {
        const int ci = idx >> 6, px = idx & 63;
        lds[idx] = in[(((size_t)(b * C_ + ci)) << 14) + p0 + px];
    }
    __syncthreads();

    const int px4 = (tid & 15) * 4;       // 4 consecutive pixels
    const int co0 = (tid >> 4) * 8;       // 8 consecutive out-channels

    float acc[8][4];
#pragma unroll
    for (int q = 0; q < 8; ++q) {
        const float bv = bias[co0 + q];
        acc[q][0] = bv; acc[q][1] = bv; acc[q][2] = bv; acc[q][3] = bv;
    }

    for (int ci = 0; ci < C_; ci += 4) {
        float xvv[4][4];
#pragma unroll
        for (int jc = 0; jc < 4; ++jc) {
            const float4 t = *(const float4*)&lds[(ci + jc) * 64 + px4];
            xvv[jc][0] = t.x; xvv[jc][1] = t.y; xvv[jc][2] = t.z; xvv[jc][3] = t.w;
        }
#pragma unroll
        for (int q = 0; q < 8; ++q) {
            const float4 wv = *(const float4*)&w[(co0 + q) * C_ + ci];
#pragma unroll
            for (int jp = 0; jp < 4; ++jp) {
                acc[q][jp] += wv.x * xvv[0][jp] + wv.y * xvv[1][jp]
                            + wv.z * xvv[2][jp] + wv.w * xvv[3][jp];
            }
        }
    }

#pragma unroll
    for (int q = 0; q < 8; ++q) {
        float4 o; o.x = acc[q][0]; o.y = acc[q][1]; o.z = acc[q][2]; o.w = acc[q][3];
        *(float4*)&out[(((size_t)(b * C_ + co0 + q)) << 14) + p0 + px4] = o;
    }
}

// ---------- depthwise 3x3, pad=1 ----------
__global__ void __launch_bounds__(256) dw_kernel(
    const float* __restrict__ in, const float* __restrict__ w,
    const float* __restrict__ bias, float* __restrict__ out)
{
    const int idx = blockIdx.x * 256 + (int)threadIdx.x;
    const int xx = idx & 255;
    const int y  = (idx >> 8) & 63;
    const int bc = idx >> 14;            // 0..255 (b*128+c)
    const int c  = bc & (C_ - 1);
    const size_t base = ((size_t)bc) << 14;

    float acc = bias[c];
#pragma unroll
    for (int ky = 0; ky < 3; ++ky) {
        const int yy = y + ky - 1;
        if (yy < 0 || yy >= H_) continue;
#pragma unroll
        for (int kx = 0; kx < 3; ++kx) {
            const int x2 = xx + kx - 1;
            if (x2 < 0 || x2 >= W_) continue;
            acc += w[c * 9 + ky * 3 + kx] * in[base + yy * 256 + x2];
        }
    }
    out[base + (y << 8) + xx] = acc;
}

extern "C" void kernel_launch(void* const* d_in, const int* in_sizes, int n_in,
                              void* d_out, int out_size, void* d_ws, size_t ws_size,
                              hipStream_t stream) {
    (void)in_sizes; (void)n_in; (void)out_size; (void)ws_size;
    const float* x     = (const float*)d_in[0];
    const float* xr    = (const float*)d_in[1];
    const float* ro    = (const float*)d_in[2];
    const float* w_rc  = (const float*)d_in[3];
    const float* b_rc  = (const float*)d_in[4];
    const float* w_dw1 = (const float*)d_in[5];
    const float* b_dw1 = (const float*)d_in[6];
    const float* w_pw1 = (const float*)d_in[7];
    const float* b_pw1 = (const float*)d_in[8];
    const float* w_dw2 = (const float*)d_in[9];
    const float* b_dw2 = (const float*)d_in[10];
    const float* w_pw2 = (const float*)d_in[11];
    const float* b_pw2 = (const float*)d_in[12];
    float* outp = (float*)d_out;

    // mm lives in the HEAD OF D_OUT (16 bytes) — consumed by shift_kernel and
    // dead before dw1 overwrites d_out. Workspace holds exactly ONE tensor.
    uint32_t* mm = (uint32_t*)d_out;
    float* bufA  = (float*)d_ws;

    // re-init min/max slots every call (nothing is re-poisoned between replays)
    hipMemsetAsync(mm, 0xFF, 8, stream);       // min slots -> max key
    hipMemsetAsync(mm + 2, 0x00, 8, stream);   // max slots -> min key

    minmax_kernel<<<64, 256, 0, stream>>>(xr, mm);
    shift_kernel<<<128 * 16, 256, 0, stream>>>(x, xr, ro, mm, bufA); // x -> ws
    pw_kernel<<<512, 256, 0, stream>>>(bufA, w_rc, b_rc, bufA);     // in-place (ws)
    dw_kernel<<<16384, 256, 0, stream>>>(bufA, w_dw1, b_dw1, outp); // ws -> out (kills mm)
    pw_kernel<<<512, 256, 0, stream>>>(outp, w_pw1, b_pw1, outp);   // in-place (out)
    dw_kernel<<<16384, 256, 0, stream>>>(outp, w_dw2, b_dw2, bufA); // out -> ws
    pw_kernel<<<512, 256, 0, stream>>>(bufA, w_pw2, b_pw2, outp);   // ws -> out (final)
}